// Round 1
// baseline (814.655 us; speedup 1.0000x reference)
//
#include <hip/hip_runtime.h>

#define NN 50000
#define NE 800000
#define DIM 128
#define NG 64
#define ETOT (NE + NN)
#define NEG_SLOPE 0.2f

// ============================ CSR build ============================

__global__ __launch_bounds__(256) void k_init(int* deg, int* fill, float* pooled, float* cnt) {
  int i = blockIdx.x * 256 + threadIdx.x;
  if (i < NN) { deg[i] = 1; fill[i] = 1; }          // 1 = self-loop
  if (i < NG * DIM) pooled[i] = 0.f;
  if (i < NG) cnt[i] = 0.f;
}

__global__ __launch_bounds__(256) void k_count(const int* __restrict__ dst, int* __restrict__ deg) {
  int e = blockIdx.x * 256 + threadIdx.x;
  if (e < NE) atomicAdd(&deg[dst[e]], 1);
}

// single-block inclusive scan -> offs[i+1] = sum(deg[0..i]), offs[0] = 0
__global__ __launch_bounds__(1024) void k_scan(const int* __restrict__ deg, int* __restrict__ offs) {
  __shared__ int wsum[16];
  __shared__ int carry_s;
  const int tid = threadIdx.x;
  const int lane = tid & 63, wid = tid >> 6;
  if (tid == 0) { carry_s = 0; offs[0] = 0; }
  __syncthreads();
  for (int base = 0; base < NN; base += 1024) {
    int i = base + tid;
    int x = (i < NN) ? deg[i] : 0;
#pragma unroll
    for (int off = 1; off < 64; off <<= 1) {
      int t = __shfl_up(x, off, 64);
      if (lane >= off) x += t;
    }
    if (lane == 63) wsum[wid] = x;
    __syncthreads();
    if (wid == 0) {
      int w = (lane < 16) ? wsum[lane] : 0;
#pragma unroll
      for (int off = 1; off < 16; off <<= 1) {
        int t = __shfl_up(w, off, 64);
        if (lane >= off) w += t;
      }
      if (lane < 16) wsum[lane] = w;
    }
    __syncthreads();
    int carry = carry_s;
    int wpre = (wid > 0) ? wsum[wid - 1] : 0;
    if (i < NN) offs[i + 1] = carry + wpre + x;
    __syncthreads();
    if (tid == 1023) carry_s = carry + wsum[15];
    __syncthreads();
  }
}

__global__ __launch_bounds__(256) void k_selfloop(const int* __restrict__ offs, int* __restrict__ csr) {
  int i = blockIdx.x * 256 + threadIdx.x;
  if (i < NN) csr[offs[i]] = i;   // slot 0 of each segment = self-loop
}

__global__ __launch_bounds__(256) void k_scatter(const int* __restrict__ src, const int* __restrict__ dst,
                                                 const int* __restrict__ offs, int* __restrict__ fill,
                                                 int* __restrict__ csr) {
  int e = blockIdx.x * 256 + threadIdx.x;
  if (e < NE) {
    int d = dst[e];
    int p = offs[d] + atomicAdd(&fill[d], 1);
    csr[p] = src[e];
  }
}

// ============================ GEMM h = X @ W  (X:[n,128], W:[128,128]) ============================
// BM=64, BK=32, block 256, thread tile 4 rows x 8 cols.

__global__ __launch_bounds__(256) void k_gemm(const float* __restrict__ X, const float* __restrict__ W,
                                              float* __restrict__ H, int n) {
  __shared__ float sA[64][36];    // [row][k], stride 36 dwords = 144B (16B aligned)
  __shared__ float sB[32][132];   // [k][col], stride 132 dwords = 528B (16B aligned)
  const int tid = threadIdx.x;
  const int tx = tid & 15;        // cols tx*8 .. +8
  const int ty = tid >> 4;        // rows ty*4 .. +4
  const int row0 = blockIdx.x * 64;
  float acc[4][8];
#pragma unroll
  for (int i = 0; i < 4; ++i)
#pragma unroll
    for (int j = 0; j < 8; ++j) acc[i][j] = 0.f;

  for (int k0 = 0; k0 < DIM; k0 += 32) {
#pragma unroll
    for (int i = 0; i < 2; ++i) {          // A tile: 64x32 floats
      int idx = tid + i * 256;
      int r = idx >> 3, c4 = idx & 7;
      int rg = row0 + r; if (rg > n - 1) rg = n - 1;
      float4 v = *(const float4*)(X + (size_t)rg * DIM + k0 + c4 * 4);
      *(float4*)&sA[r][c4 * 4] = v;
    }
#pragma unroll
    for (int i = 0; i < 4; ++i) {          // B tile: 32x128 floats
      int idx = tid + i * 256;
      int k = idx >> 5, c4 = idx & 31;
      float4 v = *(const float4*)(W + (size_t)(k0 + k) * DIM + c4 * 4);
      *(float4*)&sB[k][c4 * 4] = v;
    }
    __syncthreads();
#pragma unroll 8
    for (int k = 0; k < 32; ++k) {
      float a[4], b[8];
#pragma unroll
      for (int i = 0; i < 4; ++i) a[i] = sA[ty * 4 + i][k];
      float4 b0 = *(const float4*)&sB[k][tx * 8];
      float4 b1 = *(const float4*)&sB[k][tx * 8 + 4];
      b[0] = b0.x; b[1] = b0.y; b[2] = b0.z; b[3] = b0.w;
      b[4] = b1.x; b[5] = b1.y; b[6] = b1.z; b[7] = b1.w;
#pragma unroll
      for (int i = 0; i < 4; ++i)
#pragma unroll
        for (int j = 0; j < 8; ++j) acc[i][j] = fmaf(a[i], b[j], acc[i][j]);
    }
    __syncthreads();
  }
#pragma unroll
  for (int i = 0; i < 4; ++i) {
    int r = row0 + ty * 4 + i;
    if (r < n) {
      float4 v0 = make_float4(acc[i][0], acc[i][1], acc[i][2], acc[i][3]);
      float4 v1 = make_float4(acc[i][4], acc[i][5], acc[i][6], acc[i][7]);
      *(float4*)(H + (size_t)r * DIM + tx * 8) = v0;
      *(float4*)(H + (size_t)r * DIM + tx * 8 + 4) = v1;
    }
  }
}

// ============================ alpha_s/d[i] = h[i] . a_s / a_d ============================
// one wave per node, 2 floats per lane

__global__ __launch_bounds__(256) void k_alpha(const float* __restrict__ h, const float* __restrict__ a_s,
                                               const float* __restrict__ a_d, float* __restrict__ alpha_s,
                                               float* __restrict__ alpha_d) {
  int wave = (blockIdx.x * 256 + threadIdx.x) >> 6;
  int l = threadIdx.x & 63;
  if (wave >= NN) return;
  float2 hv = *(const float2*)(h + (size_t)wave * DIM + 2 * l);
  float2 vs = *(const float2*)(a_s + 2 * l);
  float2 vd = *(const float2*)(a_d + 2 * l);
  float ps = hv.x * vs.x + hv.y * vs.y;
  float pd = hv.x * vd.x + hv.y * vd.y;
#pragma unroll
  for (int off = 1; off < 64; off <<= 1) {
    ps += __shfl_xor(ps, off, 64);
    pd += __shfl_xor(pd, off, 64);
  }
  if (l == 0) { alpha_s[wave] = ps; alpha_d[wave] = pd; }
}

// ============================ edge softmax -> coef (CSR order) ============================
// 16 lanes per node

__global__ __launch_bounds__(256) void k_softmax(const int* __restrict__ offs, const int* __restrict__ csr,
                                                 const float* __restrict__ alpha_s, const float* __restrict__ alpha_d,
                                                 float* __restrict__ coef) {
  int tid = blockIdx.x * 256 + threadIdx.x;
  int node = tid >> 4;
  int l = tid & 15;
  if (node >= NN) return;
  int beg = offs[node], end = offs[node + 1];
  float ad = alpha_d[node];
  float m = -1e30f;
  for (int j = beg + l; j < end; j += 16) {
    float sc = alpha_s[csr[j]] + ad;
    sc = sc > 0.f ? sc : NEG_SLOPE * sc;
    m = fmaxf(m, sc);
  }
#pragma unroll
  for (int off = 1; off < 16; off <<= 1) m = fmaxf(m, __shfl_xor(m, off, 64));
  float ssum = 0.f;
  for (int j = beg + l; j < end; j += 16) {
    float sc = alpha_s[csr[j]] + ad;
    sc = sc > 0.f ? sc : NEG_SLOPE * sc;
    float ex = __expf(sc - m);
    coef[j] = ex;
    ssum += ex;
  }
#pragma unroll
  for (int off = 1; off < 16; off <<= 1) ssum += __shfl_xor(ssum, off, 64);
  float inv = 1.f / (ssum + 1e-16f);
  for (int j = beg + l; j < end; j += 16) coef[j] *= inv;
}

// ============================ aggregate: out[i] = sum_j coef[j]*h[src_j] + bias ============================
// one wave per node, float2 per lane

__global__ __launch_bounds__(256) void k_aggr(const int* __restrict__ offs, const int* __restrict__ csr,
                                              const float* __restrict__ coef, const float* __restrict__ h,
                                              const float* __restrict__ bias, float* __restrict__ out) {
  int wave = (blockIdx.x * 256 + threadIdx.x) >> 6;
  int l = threadIdx.x & 63;
  if (wave >= NN) return;
  int beg = offs[wave], end = offs[wave + 1];
  float2 acc = {0.f, 0.f};
  int j = beg;
  for (; j + 1 < end; j += 2) {
    float c0 = coef[j], c1 = coef[j + 1];
    int s0 = csr[j], s1 = csr[j + 1];
    float2 h0 = *(const float2*)(h + (size_t)s0 * DIM + 2 * l);
    float2 h1 = *(const float2*)(h + (size_t)s1 * DIM + 2 * l);
    acc.x = fmaf(c0, h0.x, acc.x); acc.y = fmaf(c0, h0.y, acc.y);
    acc.x = fmaf(c1, h1.x, acc.x); acc.y = fmaf(c1, h1.y, acc.y);
  }
  if (j < end) {
    float c0 = coef[j];
    int s0 = csr[j];
    float2 h0 = *(const float2*)(h + (size_t)s0 * DIM + 2 * l);
    acc.x = fmaf(c0, h0.x, acc.x); acc.y = fmaf(c0, h0.y, acc.y);
  }
  float2 b = *(const float2*)(bias + 2 * l);
  acc.x += b.x; acc.y += b.y;
  *(float2*)(out + (size_t)wave * DIM + 2 * l) = acc;
}

// ============================ global mean pool ============================

__global__ __launch_bounds__(256) void k_pool(const float* __restrict__ feats, const int* __restrict__ batch,
                                              float* __restrict__ pooled, float* __restrict__ cnt) {
  int wave = (blockIdx.x * 256 + threadIdx.x) >> 6;
  int l = threadIdx.x & 63;
  if (wave >= NN) return;
  int g = batch[wave];
  float2 v = *(const float2*)(feats + (size_t)wave * DIM + 2 * l);
  atomicAdd(&pooled[g * DIM + 2 * l], v.x);
  atomicAdd(&pooled[g * DIM + 2 * l + 1], v.y);
  if (l == 0) atomicAdd(&cnt[g], 1.f);
}

__global__ __launch_bounds__(256) void k_pool_norm(float* pooled, const float* __restrict__ cnt) {
  int i = blockIdx.x * 256 + threadIdx.x;
  if (i < NG * DIM) pooled[i] /= fmaxf(cnt[i >> 7], 1.f);
}

// ============================ launch ============================

static inline size_t pad256(size_t x) { return (x + 255) & ~(size_t)255; }

extern "C" void kernel_launch(void* const* d_in, const int* in_sizes, int n_in,
                              void* d_out, int out_size, void* d_ws, size_t ws_size,
                              hipStream_t stream) {
  const float* x   = (const float*)d_in[0];
  const int* ei    = (const int*)d_in[1];
  const int* batch = (const int*)d_in[2];
  const float* W1  = (const float*)d_in[3];
  const float* as1 = (const float*)d_in[4];
  const float* ad1 = (const float*)d_in[5];
  const float* b1  = (const float*)d_in[6];
  const float* W2  = (const float*)d_in[7];
  const float* as2 = (const float*)d_in[8];
  const float* ad2 = (const float*)d_in[9];
  const float* b2  = (const float*)d_in[10];

  float* out_feats = (float*)d_out;
  float* pooled    = out_feats + (size_t)NN * DIM;

  const int* src = ei;
  const int* dst = ei + NE;

  char* w = (char*)d_ws;
  float* h  = (float*)w;      w += pad256((size_t)NN * DIM * 4);
  float* f1 = (float*)w;      w += pad256((size_t)NN * DIM * 4);
  float* alpha_s = (float*)w; w += pad256((size_t)NN * 4);
  float* alpha_d = (float*)w; w += pad256((size_t)NN * 4);
  int* deg  = (int*)w;        w += pad256((size_t)NN * 4);
  int* offs = (int*)w;        w += pad256((size_t)(NN + 1) * 4);
  int* fill = (int*)w;        w += pad256((size_t)NN * 4);
  int* csr  = (int*)w;        w += pad256((size_t)ETOT * 4);
  float* coef = (float*)w;    w += pad256((size_t)ETOT * 4);
  float* cnt  = (float*)w;    w += pad256((size_t)NG * 4);

  const int NB_N = (NN + 255) / 256;            // 196
  const int NB_E = (NE + 255) / 256;            // 3125
  const int NB_W = (NN * 64 + 255) / 256;       // 12500 (one wave / node)
  const int NB_S = (NN * 16 + 255) / 256;       // 3125  (16 lanes / node)
  const int NB_G = (NN + 63) / 64;              // 782

  // CSR build (graph shared by both layers)
  k_init<<<NB_N, 256, 0, stream>>>(deg, fill, pooled, cnt);
  k_count<<<NB_E, 256, 0, stream>>>(dst, deg);
  k_scan<<<1, 1024, 0, stream>>>(deg, offs);
  k_selfloop<<<NB_N, 256, 0, stream>>>(offs, csr);
  k_scatter<<<NB_E, 256, 0, stream>>>(src, dst, offs, fill, csr);

  // layer 1
  k_gemm<<<NB_G, 256, 0, stream>>>(x, W1, h, NN);
  k_alpha<<<NB_W, 256, 0, stream>>>(h, as1, ad1, alpha_s, alpha_d);
  k_softmax<<<NB_S, 256, 0, stream>>>(offs, csr, alpha_s, alpha_d, coef);
  k_aggr<<<NB_W, 256, 0, stream>>>(offs, csr, coef, h, b1, f1);

  // layer 2
  k_gemm<<<NB_G, 256, 0, stream>>>(f1, W2, h, NN);
  k_alpha<<<NB_W, 256, 0, stream>>>(h, as2, ad2, alpha_s, alpha_d);
  k_softmax<<<NB_S, 256, 0, stream>>>(offs, csr, alpha_s, alpha_d, coef);
  k_aggr<<<NB_W, 256, 0, stream>>>(offs, csr, coef, h, b2, out_feats);

  // pool
  k_pool<<<NB_W, 256, 0, stream>>>(out_feats, batch, pooled, cnt);
  k_pool_norm<<<(NG * DIM + 255) / 256, 256, 0, stream>>>(pooled, cnt);
}

// Round 2
// 396.238 us; speedup vs baseline: 2.0560x; 2.0560x over previous
//
#include <hip/hip_runtime.h>

#define NN 50000
#define NE 800000
#define DIM 128
#define NG 64
#define ETOT (NE + NN)
#define NEG_SLOPE 0.2f
#define PB 200          // pooling blocks; chunk = 250 nodes
#define MAXLG 8         // local graph slots per block

// ============================ CSR build ============================

__global__ __launch_bounds__(256) void k_init(int* deg, int* fill, float* pooled, float* cnt) {
  int i = blockIdx.x * 256 + threadIdx.x;
  if (i < NN) { deg[i] = 1; fill[i] = 1; }          // 1 = self-loop
  if (i < NG * DIM) pooled[i] = 0.f;
  if (i < NG) cnt[i] = 0.f;
}

__global__ __launch_bounds__(256) void k_count(const int* __restrict__ dst, int* __restrict__ deg) {
  int e = blockIdx.x * 256 + threadIdx.x;
  if (e < NE) atomicAdd(&deg[dst[e]], 1);
}

// single-block inclusive scan -> offs[i+1] = sum(deg[0..i]), offs[0] = 0
__global__ __launch_bounds__(1024) void k_scan(const int* __restrict__ deg, int* __restrict__ offs) {
  __shared__ int wsum[16];
  __shared__ int carry_s;
  const int tid = threadIdx.x;
  const int lane = tid & 63, wid = tid >> 6;
  if (tid == 0) { carry_s = 0; offs[0] = 0; }
  __syncthreads();
  for (int base = 0; base < NN; base += 1024) {
    int i = base + tid;
    int x = (i < NN) ? deg[i] : 0;
#pragma unroll
    for (int off = 1; off < 64; off <<= 1) {
      int t = __shfl_up(x, off, 64);
      if (lane >= off) x += t;
    }
    if (lane == 63) wsum[wid] = x;
    __syncthreads();
    if (wid == 0) {
      int w = (lane < 16) ? wsum[lane] : 0;
#pragma unroll
      for (int off = 1; off < 16; off <<= 1) {
        int t = __shfl_up(w, off, 64);
        if (lane >= off) w += t;
      }
      if (lane < 16) wsum[lane] = w;
    }
    __syncthreads();
    int carry = carry_s;
    int wpre = (wid > 0) ? wsum[wid - 1] : 0;
    if (i < NN) offs[i + 1] = carry + wpre + x;
    __syncthreads();
    if (tid == 1023) carry_s = carry + wsum[15];
    __syncthreads();
  }
}

__global__ __launch_bounds__(256) void k_selfloop(const int* __restrict__ offs, int* __restrict__ csr) {
  int i = blockIdx.x * 256 + threadIdx.x;
  if (i < NN) csr[offs[i]] = i;   // slot 0 of each segment = self-loop
}

__global__ __launch_bounds__(256) void k_scatter(const int* __restrict__ src, const int* __restrict__ dst,
                                                 const int* __restrict__ offs, int* __restrict__ fill,
                                                 int* __restrict__ csr) {
  int e = blockIdx.x * 256 + threadIdx.x;
  if (e < NE) {
    int d = dst[e];
    int p = offs[d] + atomicAdd(&fill[d], 1);
    csr[p] = src[e];
  }
}

// ============================ GEMM h = X @ W  (X:[n,128], W:[128,128]) ============================
// BM=64, BK=32, block 256, thread tile 4 rows x 8 cols.

__global__ __launch_bounds__(256) void k_gemm(const float* __restrict__ X, const float* __restrict__ W,
                                              float* __restrict__ H, int n) {
  __shared__ float sA[64][36];
  __shared__ float sB[32][132];
  const int tid = threadIdx.x;
  const int tx = tid & 15;
  const int ty = tid >> 4;
  const int row0 = blockIdx.x * 64;
  float acc[4][8];
#pragma unroll
  for (int i = 0; i < 4; ++i)
#pragma unroll
    for (int j = 0; j < 8; ++j) acc[i][j] = 0.f;

  for (int k0 = 0; k0 < DIM; k0 += 32) {
#pragma unroll
    for (int i = 0; i < 2; ++i) {
      int idx = tid + i * 256;
      int r = idx >> 3, c4 = idx & 7;
      int rg = row0 + r; if (rg > n - 1) rg = n - 1;
      float4 v = *(const float4*)(X + (size_t)rg * DIM + k0 + c4 * 4);
      *(float4*)&sA[r][c4 * 4] = v;
    }
#pragma unroll
    for (int i = 0; i < 4; ++i) {
      int idx = tid + i * 256;
      int k = idx >> 5, c4 = idx & 31;
      float4 v = *(const float4*)(W + (size_t)(k0 + k) * DIM + c4 * 4);
      *(float4*)&sB[k][c4 * 4] = v;
    }
    __syncthreads();
#pragma unroll 8
    for (int k = 0; k < 32; ++k) {
      float a[4], b[8];
#pragma unroll
      for (int i = 0; i < 4; ++i) a[i] = sA[ty * 4 + i][k];
      float4 b0 = *(const float4*)&sB[k][tx * 8];
      float4 b1 = *(const float4*)&sB[k][tx * 8 + 4];
      b[0] = b0.x; b[1] = b0.y; b[2] = b0.z; b[3] = b0.w;
      b[4] = b1.x; b[5] = b1.y; b[6] = b1.z; b[7] = b1.w;
#pragma unroll
      for (int i = 0; i < 4; ++i)
#pragma unroll
        for (int j = 0; j < 8; ++j) acc[i][j] = fmaf(a[i], b[j], acc[i][j]);
    }
    __syncthreads();
  }
#pragma unroll
  for (int i = 0; i < 4; ++i) {
    int r = row0 + ty * 4 + i;
    if (r < n) {
      float4 v0 = make_float4(acc[i][0], acc[i][1], acc[i][2], acc[i][3]);
      float4 v1 = make_float4(acc[i][4], acc[i][5], acc[i][6], acc[i][7]);
      *(float4*)(H + (size_t)r * DIM + tx * 8) = v0;
      *(float4*)(H + (size_t)r * DIM + tx * 8 + 4) = v1;
    }
  }
}

// ============================ alpha_s/d[i] = h[i] . a_s / a_d ============================

__global__ __launch_bounds__(256) void k_alpha(const float* __restrict__ h, const float* __restrict__ a_s,
                                               const float* __restrict__ a_d, float* __restrict__ alpha_s,
                                               float* __restrict__ alpha_d) {
  int wave = (blockIdx.x * 256 + threadIdx.x) >> 6;
  int l = threadIdx.x & 63;
  if (wave >= NN) return;
  float2 hv = *(const float2*)(h + (size_t)wave * DIM + 2 * l);
  float2 vs = *(const float2*)(a_s + 2 * l);
  float2 vd = *(const float2*)(a_d + 2 * l);
  float ps = hv.x * vs.x + hv.y * vs.y;
  float pd = hv.x * vd.x + hv.y * vd.y;
#pragma unroll
  for (int off = 1; off < 64; off <<= 1) {
    ps += __shfl_xor(ps, off, 64);
    pd += __shfl_xor(pd, off, 64);
  }
  if (l == 0) { alpha_s[wave] = ps; alpha_d[wave] = pd; }
}

// ============================ edge softmax -> coef (CSR order) ============================

__global__ __launch_bounds__(256) void k_softmax(const int* __restrict__ offs, const int* __restrict__ csr,
                                                 const float* __restrict__ alpha_s, const float* __restrict__ alpha_d,
                                                 float* __restrict__ coef) {
  int tid = blockIdx.x * 256 + threadIdx.x;
  int node = tid >> 4;
  int l = tid & 15;
  if (node >= NN) return;
  int beg = offs[node], end = offs[node + 1];
  float ad = alpha_d[node];
  float m = -1e30f;
  for (int j = beg + l; j < end; j += 16) {
    float sc = alpha_s[csr[j]] + ad;
    sc = sc > 0.f ? sc : NEG_SLOPE * sc;
    m = fmaxf(m, sc);
  }
#pragma unroll
  for (int off = 1; off < 16; off <<= 1) m = fmaxf(m, __shfl_xor(m, off, 64));
  float ssum = 0.f;
  for (int j = beg + l; j < end; j += 16) {
    float sc = alpha_s[csr[j]] + ad;
    sc = sc > 0.f ? sc : NEG_SLOPE * sc;
    float ex = __expf(sc - m);
    coef[j] = ex;
    ssum += ex;
  }
#pragma unroll
  for (int off = 1; off < 16; off <<= 1) ssum += __shfl_xor(ssum, off, 64);
  float inv = 1.f / (ssum + 1e-16f);
  for (int j = beg + l; j < end; j += 16) coef[j] *= inv;
}

// ============================ aggregate ============================

__global__ __launch_bounds__(256) void k_aggr(const int* __restrict__ offs, const int* __restrict__ csr,
                                              const float* __restrict__ coef, const float* __restrict__ h,
                                              const float* __restrict__ bias, float* __restrict__ out) {
  int wave = (blockIdx.x * 256 + threadIdx.x) >> 6;
  int l = threadIdx.x & 63;
  if (wave >= NN) return;
  int beg = offs[wave], end = offs[wave + 1];
  float2 acc = {0.f, 0.f};
  int j = beg;
  for (; j + 1 < end; j += 2) {
    float c0 = coef[j], c1 = coef[j + 1];
    int s0 = csr[j], s1 = csr[j + 1];
    float2 h0 = *(const float2*)(h + (size_t)s0 * DIM + 2 * l);
    float2 h1 = *(const float2*)(h + (size_t)s1 * DIM + 2 * l);
    acc.x = fmaf(c0, h0.x, acc.x); acc.y = fmaf(c0, h0.y, acc.y);
    acc.x = fmaf(c1, h1.x, acc.x); acc.y = fmaf(c1, h1.y, acc.y);
  }
  if (j < end) {
    float c0 = coef[j];
    int s0 = csr[j];
    float2 h0 = *(const float2*)(h + (size_t)s0 * DIM + 2 * l);
    acc.x = fmaf(c0, h0.x, acc.x); acc.y = fmaf(c0, h0.y, acc.y);
  }
  float2 b = *(const float2*)(bias + 2 * l);
  acc.x += b.x; acc.y += b.y;
  *(float2*)(out + (size_t)wave * DIM + 2 * l) = acc;
}

// ============================ global mean pool (hierarchical, batch sorted) ============================
// PB blocks, each owns a contiguous chunk of nodes. Wave-private LDS accumulators
// for up to MAXLG graphs spanned by the chunk -> zero atomics on the hot path.

__global__ __launch_bounds__(256) void k_pool_partial(const float* __restrict__ feats,
                                                      const int* __restrict__ batch,
                                                      float* __restrict__ pooled, float* __restrict__ cnt) {
  __shared__ float acc[4][MAXLG][DIM];   // 16 KiB, wave-private slots
  __shared__ float lcnt[4][MAXLG];
  const int tid = threadIdx.x;
  const int wid = tid >> 6, l = tid & 63;
  for (int i = tid; i < 4 * MAXLG * DIM; i += 256) ((float*)acc)[i] = 0.f;
  if (tid < 4 * MAXLG) ((float*)lcnt)[tid] = 0.f;
  __syncthreads();

  const int chunk = (NN + PB - 1) / PB;          // 250
  const int beg = blockIdx.x * chunk;
  const int end = min(beg + chunk, NN);
  const int g0 = (beg < NN) ? batch[beg] : 0;

  for (int node = beg + wid; node < end; node += 4) {
    int lg = batch[node] - g0;
    float2 v = *(const float2*)(feats + (size_t)node * DIM + 2 * l);
    if (lg < MAXLG) {                             // each lane owns elems 2l,2l+1: no races, 2-way bank alias (free)
      acc[wid][lg][2 * l] += v.x;
      acc[wid][lg][2 * l + 1] += v.y;
      if (l == 0) lcnt[wid][lg] += 1.f;
    } else {                                      // safety net (practically never)
      atomicAdd(&pooled[(g0 + lg) * DIM + 2 * l], v.x);
      atomicAdd(&pooled[(g0 + lg) * DIM + 2 * l + 1], v.y);
      if (l == 0) atomicAdd(&cnt[g0 + lg], 1.f);
    }
  }
  __syncthreads();

  for (int i = tid; i < MAXLG * DIM; i += 256) {
    int lg = i >> 7, d = i & (DIM - 1);
    float s = acc[0][lg][d] + acc[1][lg][d] + acc[2][lg][d] + acc[3][lg][d];
    if (s != 0.f) atomicAdd(&pooled[(g0 + lg) * DIM + d], s);
  }
  if (tid < MAXLG) {
    float s = lcnt[0][tid] + lcnt[1][tid] + lcnt[2][tid] + lcnt[3][tid];
    if (s != 0.f) atomicAdd(&cnt[g0 + tid], s);
  }
}

__global__ __launch_bounds__(256) void k_pool_norm(float* pooled, const float* __restrict__ cnt) {
  int i = blockIdx.x * 256 + threadIdx.x;
  if (i < NG * DIM) pooled[i] /= fmaxf(cnt[i >> 7], 1.f);
}

// ============================ launch ============================

static inline size_t pad256(size_t x) { return (x + 255) & ~(size_t)255; }

extern "C" void kernel_launch(void* const* d_in, const int* in_sizes, int n_in,
                              void* d_out, int out_size, void* d_ws, size_t ws_size,
                              hipStream_t stream) {
  const float* x   = (const float*)d_in[0];
  const int* ei    = (const int*)d_in[1];
  const int* batch = (const int*)d_in[2];
  const float* W1  = (const float*)d_in[3];
  const float* as1 = (const float*)d_in[4];
  const float* ad1 = (const float*)d_in[5];
  const float* b1  = (const float*)d_in[6];
  const float* W2  = (const float*)d_in[7];
  const float* as2 = (const float*)d_in[8];
  const float* ad2 = (const float*)d_in[9];
  const float* b2  = (const float*)d_in[10];

  float* out_feats = (float*)d_out;
  float* pooled    = out_feats + (size_t)NN * DIM;

  const int* src = ei;
  const int* dst = ei + NE;

  char* w = (char*)d_ws;
  float* h  = (float*)w;      w += pad256((size_t)NN * DIM * 4);
  float* f1 = (float*)w;      w += pad256((size_t)NN * DIM * 4);
  float* alpha_s = (float*)w; w += pad256((size_t)NN * 4);
  float* alpha_d = (float*)w; w += pad256((size_t)NN * 4);
  int* deg  = (int*)w;        w += pad256((size_t)NN * 4);
  int* offs = (int*)w;        w += pad256((size_t)(NN + 1) * 4);
  int* fill = (int*)w;        w += pad256((size_t)NN * 4);
  int* csr  = (int*)w;        w += pad256((size_t)ETOT * 4);
  float* coef = (float*)w;    w += pad256((size_t)ETOT * 4);
  float* cnt  = (float*)w;    w += pad256((size_t)NG * 4);

  const int NB_N = (NN + 255) / 256;
  const int NB_E = (NE + 255) / 256;
  const int NB_W = (NN * 64 + 255) / 256;
  const int NB_S = (NN * 16 + 255) / 256;
  const int NB_G = (NN + 63) / 64;

  // CSR build (graph shared by both layers)
  k_init<<<NB_N, 256, 0, stream>>>(deg, fill, pooled, cnt);
  k_count<<<NB_E, 256, 0, stream>>>(dst, deg);
  k_scan<<<1, 1024, 0, stream>>>(deg, offs);
  k_selfloop<<<NB_N, 256, 0, stream>>>(offs, csr);
  k_scatter<<<NB_E, 256, 0, stream>>>(src, dst, offs, fill, csr);

  // layer 1
  k_gemm<<<NB_G, 256, 0, stream>>>(x, W1, h, NN);
  k_alpha<<<NB_W, 256, 0, stream>>>(h, as1, ad1, alpha_s, alpha_d);
  k_softmax<<<NB_S, 256, 0, stream>>>(offs, csr, alpha_s, alpha_d, coef);
  k_aggr<<<NB_W, 256, 0, stream>>>(offs, csr, coef, h, b1, f1);

  // layer 2
  k_gemm<<<NB_G, 256, 0, stream>>>(f1, W2, h, NN);
  k_alpha<<<NB_W, 256, 0, stream>>>(h, as2, ad2, alpha_s, alpha_d);
  k_softmax<<<NB_S, 256, 0, stream>>>(offs, csr, alpha_s, alpha_d, coef);
  k_aggr<<<NB_W, 256, 0, stream>>>(offs, csr, coef, h, b2, out_feats);

  // pool
  k_pool_partial<<<PB, 256, 0, stream>>>(out_feats, batch, pooled, cnt);
  k_pool_norm<<<(NG * DIM + 255) / 256, 256, 0, stream>>>(pooled, cnt);
}